// Round 1
// baseline (1011.642 us; speedup 1.0000x reference)
//
#include <hip/hip_runtime.h>
#include <stdint.h>

#define BB 64
#define TT 512
#define EE 256
#define GG 1024   // 4*HD
#define HDIM 256
#define NTAG 4

typedef _Float16 f16;
typedef _Float16 half8 __attribute__((ext_vector_type(8)));
typedef float floatx4 __attribute__((ext_vector_type(4)));

__device__ __forceinline__ int dot4i8(int a, int b, int c) {
#if __has_builtin(__builtin_amdgcn_sdot4)
  return __builtin_amdgcn_sdot4(a, b, c, false);
#else
  c += (int)(signed char)(a & 0xff)         * (int)(signed char)(b & 0xff);
  c += (int)(signed char)((a >> 8) & 0xff)  * (int)(signed char)((b >> 8) & 0xff);
  c += (int)(signed char)((a >> 16) & 0xff) * (int)(signed char)((b >> 16) & 0xff);
  c += (int)(signed char)((a >> 24) & 0xff) * (int)(signed char)((b >> 24) & 0xff);
  return c;
#endif
}

__device__ __forceinline__ float sigm(float x) {
  x = fminf(fmaxf(x, -30.f), 30.f);
  return 1.f / (1.f + __expf(-x));
}
__device__ __forceinline__ float tanh_f(float x) {
  x = fminf(fmaxf(x, -15.f), 15.f);
  float e = __expf(-2.f * x);
  return (1.f - e) / (1.f + e);
}

// ---------------- pack: w_ih -> f16 Bmat rows [2048][256]; w_hh -> i8 k4-major + row scales
__global__ void pack_kernel(const float* __restrict__ wihf, const float* __restrict__ wihb,
                            const float* __restrict__ whhf, const float* __restrict__ whhb,
                            f16* __restrict__ bmat, uint32_t* __restrict__ whhp,
                            float* __restrict__ swhh) {
  int wv = (blockIdx.x * 256 + threadIdx.x) >> 6;  // global wave 0..2047
  int lane = threadIdx.x & 63;
  if (wv >= 2048) return;
  int dir = wv >> 10;
  int g = wv & 1023;
  // Bmat (w_ih as f16)
  const float* wih = dir ? wihb : wihf;
  const float* src = wih + (size_t)g * EE + lane * 4;
  f16* bp = bmat + (size_t)wv * EE + lane * 4;
  floatx4 v = *(const floatx4*)src;
  bp[0] = (f16)v[0]; bp[1] = (f16)v[1]; bp[2] = (f16)v[2]; bp[3] = (f16)v[3];
  // w_hh quantize
  const float* whh = dir ? whhb : whhf;
  floatx4 w = *(const floatx4*)(whh + (size_t)g * EE + lane * 4);
  float am = fmaxf(fmaxf(fabsf(w[0]), fabsf(w[1])), fmaxf(fabsf(w[2]), fabsf(w[3])));
#pragma unroll
  for (int d = 1; d < 64; d <<= 1) am = fmaxf(am, __shfl_xor(am, d));
  float s = am * (1.f / 127.f);
  float inv = am > 0.f ? 127.f / am : 0.f;
  int q0 = (int)rintf(w[0] * inv);
  int q1 = (int)rintf(w[1] * inv);
  int q2 = (int)rintf(w[2] * inv);
  int q3 = (int)rintf(w[3] * inv);
  uint32_t p = (uint32_t)(q0 & 255) | ((uint32_t)(q1 & 255) << 8) |
               ((uint32_t)(q2 & 255) << 16) | ((uint32_t)(q3 & 255) << 24);
  // layout [dir][k4=lane][g]
  whhp[dir * 65536 + lane * 1024 + g] = p;
  if (lane == 0) swhh[dir * 1024 + g] = s;
}

// ---------------- GEMM: xg = embeds @ w_ih^T  (f16 MFMA, fused embedding gather)
// rows: [0,B*L) -> front (dir f, t0f..), [B*L,2B*L) -> back (dir b, t0b..)
__global__ __launch_bounds__(256) void gemm_kernel(
    const int* __restrict__ sentence, const float* __restrict__ embedding,
    const f16* __restrict__ bmat, f16* __restrict__ xgF, f16* __restrict__ xgB,
    int t0f, int t0b, int L, int Lsh) {
  __shared__ __attribute__((aligned(16))) f16 As[128][72];
  __shared__ __attribute__((aligned(16))) f16 Bs[128][72];
  int rt = blockIdx.x;
  int nt = blockIdx.y;  // 0..7
  int tid = threadIdx.x;
  int lane = tid & 63;
  int wv = tid >> 6;
  int BL = BB * L;
  int rbase = rt * 128;
  int half = (rbase >= BL) ? 1 : 0;
  int rloc0 = rbase - half * BL;
  int t0 = half ? t0b : t0f;

  floatx4 acc[4][4];
#pragma unroll
  for (int i = 0; i < 4; ++i)
#pragma unroll
    for (int j = 0; j < 4; ++j) acc[i][j] = (floatx4){0.f, 0.f, 0.f, 0.f};

  int ar = tid >> 1;    // 0..127 staging row
  int part = tid & 1;   // k-half of 64
  int rl = rloc0 + ar;
  int b_ = rl >> Lsh;
  int dt = rl & (L - 1);
  int t_ = t0 + dt;
  int sidx = sentence[b_ * TT + t_];
  const float* arow = embedding + (size_t)sidx * EE + part * 32;
  const f16* brow = bmat + ((size_t)(half * 1024 + nt * 128 + ar)) * EE + part * 32;
  int wm = (wv >> 1) * 64, wn = (wv & 1) * 64;

  for (int kk = 0; kk < 4; ++kk) {
    int k0 = kk * 64;
    // stage A (gather f32 -> f16)
#pragma unroll
    for (int i = 0; i < 4; ++i) {
      floatx4 a0 = *(const floatx4*)(arow + k0 + i * 8);
      floatx4 a1 = *(const floatx4*)(arow + k0 + i * 8 + 4);
      union { f16 h[8]; uint4 u; } cv;
      cv.h[0] = (f16)a0[0]; cv.h[1] = (f16)a0[1]; cv.h[2] = (f16)a0[2]; cv.h[3] = (f16)a0[3];
      cv.h[4] = (f16)a1[0]; cv.h[5] = (f16)a1[1]; cv.h[6] = (f16)a1[2]; cv.h[7] = (f16)a1[3];
      *(uint4*)(&As[ar][part * 32 + i * 8]) = cv.u;
    }
    // stage B (f16 copy)
#pragma unroll
    for (int i = 0; i < 4; ++i) {
      uint4 bv = *(const uint4*)(brow + k0 + i * 8);
      *(uint4*)(&Bs[ar][part * 32 + i * 8]) = bv;
    }
    __syncthreads();
#pragma unroll
    for (int kf = 0; kf < 2; ++kf) {
      int ko = kf * 32 + (lane >> 4) * 8;
      half8 af[4], bf[4];
#pragma unroll
      for (int mi = 0; mi < 4; ++mi)
        af[mi] = *(const half8*)(&As[wm + mi * 16 + (lane & 15)][ko]);
#pragma unroll
      for (int ni = 0; ni < 4; ++ni)
        bf[ni] = *(const half8*)(&Bs[wn + ni * 16 + (lane & 15)][ko]);
#pragma unroll
      for (int mi = 0; mi < 4; ++mi)
#pragma unroll
        for (int ni = 0; ni < 4; ++ni)
          acc[mi][ni] = __builtin_amdgcn_mfma_f32_16x16x32_f16(af[mi], bf[ni], acc[mi][ni], 0, 0, 0);
    }
    __syncthreads();
  }
  // epilogue: C layout col=lane&15, row=(lane>>4)*4+r
  f16* out = half ? xgB : xgF;
#pragma unroll
  for (int mi = 0; mi < 4; ++mi) {
#pragma unroll
    for (int ni = 0; ni < 4; ++ni) {
      int rowl = wm + mi * 16 + (lane >> 4) * 4;
      int coll = nt * 128 + wn + ni * 16 + (lane & 15);
#pragma unroll
      for (int r = 0; r < 4; ++r) {
        out[(size_t)(rloc0 + rowl + r) * 1024 + coll] = (f16)acc[mi][ni][r];
      }
    }
  }
}

// ---------------- recurrence: 128 WGs (b,dir), 512 threads, i8 reg-resident W_hh
__global__ __launch_bounds__(512, 2) void rec_kernel(
    const int* __restrict__ length, const f16* __restrict__ xgF, const f16* __restrict__ xgB,
    const uint32_t* __restrict__ whhp, const float* __restrict__ swhh,
    const float* __restrict__ b_f, const float* __restrict__ b_b,
    const float* __restrict__ w_out, float* __restrict__ featf, float* __restrict__ featb,
    float* __restrict__ hstate, float* __restrict__ cstate,
    int t0f, int t0b, int L, int first) {
  __shared__ __attribute__((aligned(16))) uint32_t hq4[64];
  __shared__ float gacts[1024];
  __shared__ float fpart[4][4];

  int wid = blockIdx.x;
  int b = wid >> 1, dir = wid & 1;
  int tid = threadIdx.x;
  int lane = tid & 63;
  int wv = tid >> 6;
  int g0 = tid, g1 = tid + 512;
  int len = length[b];

  // register-resident quantized weights: 2 gate rows per thread
  uint32_t wr0[64], wr1[64];
  const uint32_t* wp = whhp + dir * 65536;
#pragma unroll
  for (int q = 0; q < 64; ++q) { wr0[q] = wp[q * 1024 + g0]; wr1[q] = wp[q * 1024 + g1]; }
  float sw0 = swhh[dir * 1024 + g0] * (1.f / 127.f);
  float sw1 = swhh[dir * 1024 + g1] * (1.f / 127.f);
  const float* bias = dir ? b_b : b_f;
  float bi0 = bias[g0], bi1 = bias[g1];

  float wo0 = 0.f, wo1 = 0.f, wo2 = 0.f, wo3 = 0.f;
  float h = 0.f, c = 0.f;
  if (tid < 256) {
    wo0 = w_out[0 * 512 + dir * 256 + tid];
    wo1 = w_out[1 * 512 + dir * 256 + tid];
    wo2 = w_out[2 * 512 + dir * 256 + tid];
    wo3 = w_out[3 * 512 + dir * 256 + tid];
    if (!first) {
      h = hstate[(dir * BB + b) * HDIM + tid];
      c = cstate[(dir * BB + b) * HDIM + tid];
    }
  }
  float* featX = dir ? featb : featf;
  const f16* xg = dir ? xgB : xgF;

  // initial pack of h -> hq4
  if (tid < 256) {
    int q = (int)rintf(h * 127.f);
    q = max(-127, min(127, q));
    int qb1 = __shfl(q, (lane + 1) & 63);
    int qb2 = __shfl(q, (lane + 2) & 63);
    int qb3 = __shfl(q, (lane + 3) & 63);
    if ((lane & 3) == 0)
      hq4[tid >> 2] = (uint32_t)(q & 255) | ((uint32_t)(qb1 & 255) << 8) |
                      ((uint32_t)(qb2 & 255) << 16) | ((uint32_t)(qb3 & 255) << 24);
  }

  int tlo = dir ? t0b : t0f;
  int thi = min(tlo + L, len);
  // zero-fill masked feats in this chunk
  int zstart = thi > tlo ? thi : tlo;
  int zcount = (tlo + L - zstart) * 4;
  size_t zbase = ((size_t)b * TT + zstart) * 4;
  for (int u = tid; u < zcount; u += 512) featX[zbase + u] = 0.f;
  __syncthreads();

  auto step = [&](int t) {
    // xg loads (independent of state - issue first)
    size_t xoff = ((size_t)(b * L + (t - tlo)) << 10);
    float xv0 = (float)xg[xoff + g0];
    float xv1 = (float)xg[xoff + g1];
    // broadcast h (i8 packed) from LDS
    uint32_t hq[64];
#pragma unroll
    for (int q2 = 0; q2 < 16; ++q2) {
      uint4 v = *((const uint4*)hq4 + q2);
      hq[q2 * 4 + 0] = v.x; hq[q2 * 4 + 1] = v.y; hq[q2 * 4 + 2] = v.z; hq[q2 * 4 + 3] = v.w;
    }
    int a0 = 0, a1 = 0;
#pragma unroll
    for (int q = 0; q < 64; ++q) {
      a0 = dot4i8(wr0[q], hq[q], a0);
      a1 = dot4i8(wr1[q], hq[q], a1);
    }
    float p0 = xv0 + bi0 + sw0 * (float)a0;  // i (tid<256) or f gate
    float p1 = xv1 + bi1 + sw1 * (float)a1;  // g (tid<256, tanh) or o gate
    float act0 = sigm(p0);
    float act1 = (tid < 256) ? tanh_f(p1) : sigm(p1);
    gacts[g0] = act0;
    gacts[g1] = act1;
    __syncthreads();  // B1
    if (tid < 256) {
      float iv = gacts[tid], fv = gacts[tid + 256], gv = gacts[tid + 512], ov = gacts[tid + 768];
      c = fv * c + iv * gv;
      h = ov * tanh_f(c);
      // quantize new h, pack 4 lanes/uint
      int q = (int)rintf(h * 127.f);
      q = max(-127, min(127, q));
      int qb1 = __shfl(q, (lane + 1) & 63);
      int qb2 = __shfl(q, (lane + 2) & 63);
      int qb3 = __shfl(q, (lane + 3) & 63);
      if ((lane & 3) == 0)
        hq4[tid >> 2] = (uint32_t)(q & 255) | ((uint32_t)(qb1 & 255) << 8) |
                        ((uint32_t)(qb2 & 255) << 16) | ((uint32_t)(qb3 & 255) << 24);
      // feats partials: reduce h*w_out over 256 dims (4 waves)
      float p0f = h * wo0, p1f = h * wo1, p2f = h * wo2, p3f = h * wo3;
#pragma unroll
      for (int d = 1; d < 64; d <<= 1) {
        p0f += __shfl_xor(p0f, d);
        p1f += __shfl_xor(p1f, d);
        p2f += __shfl_xor(p2f, d);
        p3f += __shfl_xor(p3f, d);
      }
      if (lane == 0) { fpart[wv][0] = p0f; fpart[wv][1] = p1f; fpart[wv][2] = p2f; fpart[wv][3] = p3f; }
    }
    __syncthreads();  // B2
    if (tid < 4) {
      featX[((size_t)b * TT + t) * 4 + tid] =
          fpart[0][tid] + fpart[1][tid] + fpart[2][tid] + fpart[3][tid];
    }
  };

  if (dir == 0) {
    for (int t = tlo; t < thi; ++t) step(t);
  } else {
    for (int t = thi - 1; t >= tlo; --t) step(t);
  }

  if (tid < 256) {
    hstate[(dir * BB + b) * HDIM + tid] = h;
    cstate[(dir * BB + b) * HDIM + tid] = c;
  }
}

// ---------------- CRF: numerator + forward algorithm, one wave per batch
__global__ void crf_kernel(const int* __restrict__ tags, const int* __restrict__ length,
                           const float* __restrict__ featf, const float* __restrict__ featb,
                           const float* __restrict__ b_out, const float* __restrict__ start_trans,
                           const float* __restrict__ end_trans, const float* __restrict__ trans,
                           float* __restrict__ res) {
  int b = blockIdx.x;
  int lane = threadIdx.x;
  int len = length[b];
  float bo = lane < NTAG ? b_out[lane] : 0.f;
  float tr0 = lane < NTAG ? trans[0 * 4 + lane] : 0.f;
  float tr1 = lane < NTAG ? trans[1 * 4 + lane] : 0.f;
  float tr2 = lane < NTAG ? trans[2 * 4 + lane] : 0.f;
  float tr3 = lane < NTAG ? trans[3 * 4 + lane] : 0.f;
  float st = lane < NTAG ? start_trans[lane] : 0.f;
  float en = lane < NTAG ? end_trans[lane] : 0.f;
  const int* tg = tags + b * TT;

  float e = 0.f;
  if (lane < NTAG)
    e = featf[((size_t)b * TT) * 4 + lane] + featb[((size_t)b * TT) * 4 + lane] + bo;
  int prev = tg[0];
  float alpha = st + e;
  float num = __shfl(st, prev) + __shfl(e, prev);
  for (int t = 1; t < len; ++t) {
    if (lane < NTAG)
      e = featf[((size_t)b * TT + t) * 4 + lane] + featb[((size_t)b * TT + t) * 4 + lane] + bo;
    float a0 = __shfl(alpha, 0), a1 = __shfl(alpha, 1), a2 = __shfl(alpha, 2), a3 = __shfl(alpha, 3);
    float v0 = a0 + tr0, v1 = a1 + tr1, v2 = a2 + tr2, v3 = a3 + tr3;
    float mx = fmaxf(fmaxf(v0, v1), fmaxf(v2, v3));
    float sm = __expf(v0 - mx) + __expf(v1 - mx) + __expf(v2 - mx) + __expf(v3 - mx);
    float anew = mx + __logf(sm) + e;
    int cur = tg[t];
    num += __shfl(e, cur) + trans[prev * 4 + cur];
    alpha = anew;
    prev = cur;
  }
  num += __shfl(en, prev);
  float v = alpha + en;
  float z0 = __shfl(v, 0), z1 = __shfl(v, 1), z2 = __shfl(v, 2), z3 = __shfl(v, 3);
  float mx = fmaxf(fmaxf(z0, z1), fmaxf(z2, z3));
  float logZ = mx + __logf(__expf(z0 - mx) + __expf(z1 - mx) + __expf(z2 - mx) + __expf(z3 - mx));
  if (lane == 0) res[b] = num - logZ;
}

__global__ void loss_kernel(const float* __restrict__ res, float* __restrict__ out) {
  int lane = threadIdx.x;
  float v = res[lane];
#pragma unroll
  for (int d = 1; d < 64; d <<= 1) v += __shfl_xor(v, d);
  if (lane == 0) out[0] = -v * (1.f / 64.f);
}

extern "C" void kernel_launch(void* const* d_in, const int* in_sizes, int n_in,
                              void* d_out, int out_size, void* d_ws, size_t ws_size,
                              hipStream_t stream) {
  (void)in_sizes; (void)n_in; (void)out_size;
  const int* sentence = (const int*)d_in[0];
  const int* tags = (const int*)d_in[1];
  const int* length = (const int*)d_in[3];
  const float* embedding = (const float*)d_in[4];
  const float* w_ih_f = (const float*)d_in[5];
  const float* w_hh_f = (const float*)d_in[6];
  const float* b_f = (const float*)d_in[7];
  const float* w_ih_b = (const float*)d_in[8];
  const float* w_hh_b = (const float*)d_in[9];
  const float* b_b = (const float*)d_in[10];
  const float* w_out = (const float*)d_in[11];
  const float* b_out = (const float*)d_in[12];
  const float* start_trans = (const float*)d_in[13];
  const float* end_trans = (const float*)d_in[14];
  const float* trans = (const float*)d_in[15];

  char* ws = (char*)d_ws;
  size_t off = 0;
  auto take = [&](size_t bytes) -> char* {
    char* p = ws + off;
    off = (off + bytes + 255) & ~(size_t)255;
    return p;
  };
  f16* bmat = (f16*)take((size_t)2048 * 256 * 2);
  uint32_t* whhp = (uint32_t*)take((size_t)2 * 64 * 1024 * 4);
  float* swhh = (float*)take((size_t)2 * 1024 * 4);
  float* featf = (float*)take((size_t)BB * TT * NTAG * 4);
  float* featb = (float*)take((size_t)BB * TT * NTAG * 4);
  float* hstate = (float*)take((size_t)2 * BB * HDIM * 4);
  float* cstate = (float*)take((size_t)2 * BB * HDIM * 4);
  float* res = (float*)take(256);
  size_t fixed = off;

  int L = TT, Lsh = 9;
  while (L > 32 && fixed + (size_t)BB * L * 1024 * 4 > ws_size) { L >>= 1; Lsh--; }
  f16* xgF = (f16*)take((size_t)BB * L * 1024 * 2);
  f16* xgB = (f16*)take((size_t)BB * L * 1024 * 2);
  int NC = TT / L;

  hipLaunchKernelGGL(pack_kernel, dim3(512), dim3(256), 0, stream,
                     w_ih_f, w_ih_b, w_hh_f, w_hh_b, bmat, whhp, swhh);

  for (int cidx = 0; cidx < NC; ++cidx) {
    int t0f_ = cidx * L;
    int t0b_ = TT - (cidx + 1) * L;
    hipLaunchKernelGGL(gemm_kernel, dim3(2 * BB * L / 128, 8), dim3(256), 0, stream,
                       sentence, embedding, bmat, xgF, xgB, t0f_, t0b_, L, Lsh);
    hipLaunchKernelGGL(rec_kernel, dim3(128), dim3(512), 0, stream,
                       length, xgF, xgB, whhp, swhh, b_f, b_b, w_out,
                       featf, featb, hstate, cstate, t0f_, t0b_, L, cidx == 0 ? 1 : 0);
  }
  hipLaunchKernelGGL(crf_kernel, dim3(BB), dim3(64), 0, stream,
                     tags, length, featf, featb, b_out, start_trans, end_trans, trans, res);
  hipLaunchKernelGGL(loss_kernel, dim3(1), dim3(64), 0, stream, res, (float*)d_out);
}